// Round 1
// baseline (2440.341 us; speedup 1.0000x reference)
//
#include <hip/hip_runtime.h>
#include <math.h>

#define NTOT  65536
#define DLAT  256
#define KCB   4096
#define CIN   256
#define HWSZ  4096

// workspace float offsets
#define OFF_ZPT   0u            // [256][65536] f32
#define OFF_EMBT  16777216u     // [256][4096]  f32
#define OFF_WT    17825792u     // [256][256]   f32
#define OFF_ENORM 17891328u     // [4096]       f32
#define OFF_RNORM 17895424u     // [65536]      f32
#define OFF_IDX   17960960u     // [65536]      i32
// total 18026496 floats = 72.1 MB

__global__ __launch_bounds__(256) void wt_kernel(const float* __restrict__ w, float* __restrict__ wT) {
    int t = blockIdx.x * 256 + threadIdx.x;     // 65536
    int o = t >> 8, c = t & 255;
    wT[c * 256 + o] = w[t];
}

__global__ __launch_bounds__(256) void et_kernel(const float* __restrict__ emb, float* __restrict__ embT) {
    int t = blockIdx.x * 256 + threadIdx.x;     // 1048576
    int k = t >> 8, d = t & 255;
    embT[d * KCB + k] = emb[t];
}

__global__ __launch_bounds__(64) void enorm_kernel(const float* __restrict__ emb, float* __restrict__ enorm) {
    int k = blockIdx.x;
    int lane = threadIdx.x;
    double a = 0.0;
    #pragma unroll
    for (int i = 0; i < 4; ++i) {
        float v = emb[k * DLAT + lane + i * 64];
        a = fma((double)v, (double)v, a);
    }
    #pragma unroll
    for (int off = 32; off > 0; off >>= 1) a += __shfl_down(a, off);
    if (lane == 0) enorm[k] = (float)a;   // single rounding to f32
}

__global__ __launch_bounds__(256) void rnorm_kernel(const float* __restrict__ zpT, float* __restrict__ rnorm) {
    int n = blockIdx.x * 256 + threadIdx.x;
    double a = 0.0;
    for (int o = 0; o < DLAT; ++o) {
        float v = zpT[(size_t)o * NTOT + n];
        a = fma((double)v, (double)v, a);
    }
    rnorm[n] = (float)a;                  // single rounding to f32
}

// zpT[o][n] = sum_c z[b][c][hw] * wT[c][o] + bias[o]
__global__ __launch_bounds__(256) void proj_kernel(const float* __restrict__ z, const float* __restrict__ wT,
                                                   const float* __restrict__ bias, float* __restrict__ zpT) {
    __shared__ float zT[16][128];
    __shared__ float wt[16][64];
    int n0 = blockIdx.x * 128;
    int o0 = blockIdx.y * 64;
    int t = threadIdx.x;
    int tm = t & 15, tn = t >> 4;
    int b = n0 >> 12;            // 128 | 4096 -> n-tile stays within one b
    int hw0 = n0 & 4095;
    float acc[8][4] = {};
    for (int c0 = 0; c0 < CIN; c0 += 16) {
        __syncthreads();
        #pragma unroll
        for (int i = 0; i < 2; ++i) {
            int e4 = t + i * 256;               // 0..511 float4 slots (16x128)
            int cc = e4 >> 5, c4 = e4 & 31;
            float4 v = *(const float4*)(z + (size_t)(b * CIN + c0 + cc) * HWSZ + hw0 + c4 * 4);
            *(float4*)&zT[cc][c4 * 4] = v;
        }
        {
            int cc = t >> 4, c4 = t & 15;       // 16x64 = 256 float4 slots
            float4 v = *(const float4*)(wT + (size_t)(c0 + cc) * 256 + o0 + c4 * 4);
            *(float4*)&wt[cc][c4 * 4] = v;
        }
        __syncthreads();
        #pragma unroll
        for (int d = 0; d < 16; ++d) {
            float4 a0 = *(const float4*)&zT[d][tm * 8];
            float4 a1 = *(const float4*)&zT[d][tm * 8 + 4];
            float4 bv = *(const float4*)&wt[d][tn * 4];
            float a[8] = {a0.x,a0.y,a0.z,a0.w,a1.x,a1.y,a1.z,a1.w};
            float bb[4] = {bv.x,bv.y,bv.z,bv.w};
            #pragma unroll
            for (int i = 0; i < 8; ++i)
                #pragma unroll
                for (int j = 0; j < 4; ++j)
                    acc[i][j] = fmaf(a[i], bb[j], acc[i][j]);
        }
    }
    #pragma unroll
    for (int j = 0; j < 4; ++j) {
        int o = o0 + tn * 4 + j;
        float bv = bias[o];
        #pragma unroll
        for (int i = 0; i < 8; ++i) {
            int n = n0 + tm * 8 + i;
            zpT[(size_t)o * NTOT + n] = acc[i][j] + bv;
        }
    }
}

// fused distance + argmin: per block 128 rows x all 4096 codes
__global__ __launch_bounds__(256) void argmin_kernel(const float* __restrict__ zpT, const float* __restrict__ embT,
                                                     const float* __restrict__ enorm, const float* __restrict__ rnorm,
                                                     int* __restrict__ idx) {
    __shared__ float zT[16][128];
    __shared__ float eT[16][64];
    __shared__ float en_s[64];
    __shared__ float rv[128][17];
    __shared__ int   ri[128][17];
    int n0 = blockIdx.x * 128;
    int t = threadIdx.x;
    int tm = t & 15, tn = t >> 4;
    float best[8];
    int bidx[8];
    float rn[8];
    #pragma unroll
    for (int i = 0; i < 8; ++i) {
        best[i] = INFINITY; bidx[i] = 0;
        rn[i] = rnorm[n0 + tm * 8 + i];
    }
    for (int k0 = 0; k0 < KCB; k0 += 64) {
        __syncthreads();                         // protect en_s/tiles from prev epilogue readers
        if (t < 64) en_s[t] = enorm[k0 + t];
        float acc[8][4] = {};
        for (int d0 = 0; d0 < DLAT; d0 += 16) {
            if (d0) __syncthreads();
            #pragma unroll
            for (int i = 0; i < 2; ++i) {
                int e4 = t + i * 256;
                int cc = e4 >> 5, c4 = e4 & 31;
                float4 v = *(const float4*)(zpT + (size_t)(d0 + cc) * NTOT + n0 + c4 * 4);
                *(float4*)&zT[cc][c4 * 4] = v;
            }
            {
                int cc = t >> 4, c4 = t & 15;
                float4 v = *(const float4*)(embT + (size_t)(d0 + cc) * KCB + k0 + c4 * 4);
                *(float4*)&eT[cc][c4 * 4] = v;
            }
            __syncthreads();
            // chunked accumulation: 16-term partial then fold into acc (tighter f32 error)
            float cacc[8][4] = {};
            #pragma unroll
            for (int d = 0; d < 16; ++d) {
                float4 a0 = *(const float4*)&zT[d][tm * 8];
                float4 a1 = *(const float4*)&zT[d][tm * 8 + 4];
                float4 bv = *(const float4*)&eT[d][tn * 4];
                float a[8] = {a0.x,a0.y,a0.z,a0.w,a1.x,a1.y,a1.z,a1.w};
                float bb[4] = {bv.x,bv.y,bv.z,bv.w};
                #pragma unroll
                for (int i = 0; i < 8; ++i)
                    #pragma unroll
                    for (int j = 0; j < 4; ++j)
                        cacc[i][j] = fmaf(a[i], bb[j], cacc[i][j]);
            }
            #pragma unroll
            for (int i = 0; i < 8; ++i)
                #pragma unroll
                for (int j = 0; j < 4; ++j)
                    acc[i][j] += cacc[i][j];
        }
        // dist = fl(fl(rn - 2*dot) + en); strict < keeps lowest index (k ascending)
        #pragma unroll
        for (int j = 0; j < 4; ++j) {
            int g = k0 + tn * 4 + j;
            float en = en_s[tn * 4 + j];
            #pragma unroll
            for (int i = 0; i < 8; ++i) {
                float s1 = rn[i] - 2.0f * acc[i][j];
                float dist = s1 + en;
                if (dist < best[i]) { best[i] = dist; bidx[i] = g; }
            }
        }
    }
    __syncthreads();
    #pragma unroll
    for (int i = 0; i < 8; ++i) {
        rv[tm * 8 + i][tn] = best[i];
        ri[tm * 8 + i][tn] = bidx[i];
    }
    __syncthreads();
    if (t < 128) {
        float bv = rv[t][0]; int bi = ri[t][0];
        #pragma unroll
        for (int q = 1; q < 16; ++q) {
            float v = rv[t][q]; int iq = ri[t][q];
            if (v < bv || (v == bv && iq < bi)) { bv = v; bi = iq; }
        }
        idx[n0 + t] = bi;
    }
}

// out[b][o][hw] = zp + (emb[idx][o] - zp)   (straight-through, f32-faithful)
__global__ __launch_bounds__(256) void out_kernel(const float* __restrict__ zpT, const float* __restrict__ emb,
                                                  const int* __restrict__ idx, float* __restrict__ out) {
    int e = blockIdx.x * 256 + threadIdx.x;
    int hw = e & 4095;
    int o = (e >> 12) & 255;
    int b = e >> 20;
    int n = (b << 12) | hw;
    float zp = zpT[(size_t)o * NTOT + n];
    float ev = emb[idx[n] * DLAT + o];
    float st = ev - zp;
    out[e] = zp + st;
}

extern "C" void kernel_launch(void* const* d_in, const int* in_sizes, int n_in,
                              void* d_out, int out_size, void* d_ws, size_t ws_size,
                              hipStream_t stream) {
    const float* z    = (const float*)d_in[0];
    const float* w    = (const float*)d_in[1];
    const float* bias = (const float*)d_in[2];
    const float* emb  = (const float*)d_in[3];
    float* ws = (float*)d_ws;
    float* zpT   = ws + OFF_ZPT;
    float* embT  = ws + OFF_EMBT;
    float* wT    = ws + OFF_WT;
    float* enorm = ws + OFF_ENORM;
    float* rnorm = ws + OFF_RNORM;
    int*   idx   = (int*)(ws + OFF_IDX);
    float* out   = (float*)d_out;

    hipLaunchKernelGGL(wt_kernel,     dim3(256),      dim3(256), 0, stream, w, wT);
    hipLaunchKernelGGL(et_kernel,     dim3(4096),     dim3(256), 0, stream, emb, embT);
    hipLaunchKernelGGL(enorm_kernel,  dim3(4096),     dim3(64),  0, stream, emb, enorm);
    hipLaunchKernelGGL(proj_kernel,   dim3(512, 4),   dim3(256), 0, stream, z, wT, bias, zpT);
    hipLaunchKernelGGL(rnorm_kernel,  dim3(256),      dim3(256), 0, stream, zpT, rnorm);
    hipLaunchKernelGGL(argmin_kernel, dim3(512),      dim3(256), 0, stream, zpT, embT, enorm, rnorm, idx);
    hipLaunchKernelGGL(out_kernel,    dim3(65536),    dim3(256), 0, stream, zpT, emb, idx, out);
}